// Round 1
// baseline (7813.244 us; speedup 1.0000x reference)
//
#include <hip/hip_runtime.h>

// LSTM: 4 layers, T=512, B=256, INPUT=100, H=128, gates=512 (i,f,g,o)
// Strategy (round 0, all fp32 for correctness):
//   per layer, per T-chunk (Tc=64):
//     1) gemm_xg: xg[t,b,j] = x[t,b,:]@w_ih[j,:] + b_ih[j] + b_hh[j]  (parallel GEMM)
//     2) lstm_rec: sequential scan; 256 blocks (1 batch row each), 512 threads
//        (1 gate each, w_hh row held in 128 VGPRs), h broadcast via LDS.
//   Layers 1-3 run in-place on the io buffer (read x_t then overwrite with h_t,
//   per-row, launches serialize per chunk -> safe).
// ws layout: io [512*256*128] f32 @0 (67MB) | xg [64*256*512] f32 @67MB (33.5MB)
//            | hstate,cstate [256*128] f32 @100.6MB  => ~101MB total.

#define TSTEPS 512
#define BATCH  256
#define HID    128
#define GATES  512
#define TC     64

__device__ __forceinline__ float sigmoid_f(float x) {
    return 1.0f / (1.0f + __expf(-x));
}
__device__ __forceinline__ float tanh_f(float x) {
    float e = __expf(2.0f * x);
    return 1.0f - 2.0f / (e + 1.0f);
}

// ---------------- input-projection GEMM ----------------
// C[r, j] = sum_k A[row r, k] * W[j, k] + b_ih[j] + b_hh[j]
// rows r = q*256 + b for t = t0+q, q in [0,TC); cols j in [0,512)
// A: L0 ? [B, T, K] : [T, B, K] (row-major). 64x64 tile, 256 threads, 4x4 micro.
template<int K, bool L0>
__global__ __launch_bounds__(256)
void gemm_xg(const float* __restrict__ A, const float* __restrict__ W,
             const float* __restrict__ bih, const float* __restrict__ bhh,
             float* __restrict__ XG, int t0)
{
    __shared__ float As[64][68];  // As[kk][row]   (transposed tiles)
    __shared__ float Bs[64][68];  // Bs[kk][col]
    const int tid = threadIdx.x;
    const int bm  = blockIdx.x;        // row tile: 0..255
    const int j0  = blockIdx.y * 64;   // gate col offset
    const int ty  = tid >> 4, tx = tid & 15;
    const int R0  = bm * 64;

    float acc[4][4] = {};

    for (int kt = 0; kt < K; kt += 64) {
        // A tile: wave-uniform row, coalesced along k
        #pragma unroll
        for (int i = 0; i < 16; ++i) {
            int f = tid + 256 * i;
            int r = f >> 6, kk = f & 63;
            int Rg = R0 + r;
            int q = Rg >> 8, b = Rg & 255;
            int t = t0 + q;
            int k = kt + kk;
            float v = 0.0f;
            if (k < K) {
                int idx = L0 ? (b * TSTEPS + t) * K + k
                             : (t * BATCH + b) * K + k;
                v = A[idx];
            }
            As[kk][r] = v;
        }
        // B tile: coalesced along k within each gate row
        #pragma unroll
        for (int i = 0; i < 16; ++i) {
            int f = tid + 256 * i;
            int col = f >> 6, kk = f & 63;
            int k = kt + kk;
            Bs[kk][col] = (k < K) ? W[(j0 + col) * K + k] : 0.0f;
        }
        __syncthreads();
        #pragma unroll
        for (int kk = 0; kk < 64; ++kk) {
            float4 a4 = *(const float4*)&As[kk][ty * 4];
            float4 b4 = *(const float4*)&Bs[kk][tx * 4];
            float aa[4] = {a4.x, a4.y, a4.z, a4.w};
            float bb[4] = {b4.x, b4.y, b4.z, b4.w};
            #pragma unroll
            for (int ii = 0; ii < 4; ++ii)
                #pragma unroll
                for (int jj = 0; jj < 4; ++jj)
                    acc[ii][jj] = fmaf(aa[ii], bb[jj], acc[ii][jj]);
        }
        __syncthreads();
    }

    float4 bi = *(const float4*)&bih[j0 + tx * 4];
    float4 bh = *(const float4*)&bhh[j0 + tx * 4];
    float bsum[4] = {bi.x + bh.x, bi.y + bh.y, bi.z + bh.z, bi.w + bh.w};
    #pragma unroll
    for (int ii = 0; ii < 4; ++ii) {
        int Rg = R0 + ty * 4 + ii;
        float4 st = {acc[ii][0] + bsum[0], acc[ii][1] + bsum[1],
                     acc[ii][2] + bsum[2], acc[ii][3] + bsum[3]};
        *(float4*)&XG[Rg * GATES + j0 + tx * 4] = st;
    }
}

// ---------------- recurrent scan ----------------
// One block per batch row; thread j owns gate j with w_hh[j,:] in 128 VGPRs.
__global__ __launch_bounds__(512)
void lstm_rec(const float* __restrict__ XG, const float* __restrict__ Whh,
              float* __restrict__ Hout,     // io buffer [T,B,128]
              float* __restrict__ hstate, float* __restrict__ cstate,
              int t0, int first)
{
    const int b = blockIdx.x;
    const int j = threadIdx.x;  // gate index 0..511
    __shared__ float h_lds[HID];
    __shared__ float g_lds[GATES];

    // w_hh row j -> registers (L2-hot after first touch)
    float w[HID];
    #pragma unroll
    for (int kk = 0; kk < 32; ++kk) {
        float4 v = *(const float4*)(Whh + j * HID + kk * 4);
        w[4 * kk + 0] = v.x; w[4 * kk + 1] = v.y;
        w[4 * kk + 2] = v.z; w[4 * kk + 3] = v.w;
    }

    float c = 0.0f;
    if (j < HID) {
        c        = first ? 0.0f : cstate[b * HID + j];
        h_lds[j] = first ? 0.0f : hstate[b * HID + j];
    }
    __syncthreads();

    float xg_val = XG[(0 * BATCH + b) * GATES + j];
    for (int q = 0; q < TC; ++q) {
        float xg_next = 0.0f;
        if (q + 1 < TC) xg_next = XG[((q + 1) * BATCH + b) * GATES + j];  // prefetch

        // g_j = xg + sum_k w[j,k] * h[k]   (4 accumulators to break dep chain)
        float a0 = xg_val, a1 = 0.0f, a2 = 0.0f, a3 = 0.0f;
        #pragma unroll
        for (int kk = 0; kk < 32; ++kk) {
            float4 hv = *(const float4*)&h_lds[kk * 4];  // broadcast read
            a0 = fmaf(w[4 * kk + 0], hv.x, a0);
            a1 = fmaf(w[4 * kk + 1], hv.y, a1);
            a2 = fmaf(w[4 * kk + 2], hv.z, a2);
            a3 = fmaf(w[4 * kk + 3], hv.w, a3);
        }
        g_lds[j] = (a0 + a1) + (a2 + a3);
        __syncthreads();

        if (j < HID) {
            float ig = sigmoid_f(g_lds[j]);
            float fg = sigmoid_f(g_lds[HID + j]);
            float gg = tanh_f(g_lds[2 * HID + j]);
            float og = sigmoid_f(g_lds[3 * HID + j]);
            c = fg * c + ig * gg;
            float h = og * tanh_f(c);
            h_lds[j] = h;
            Hout[((t0 + q) * BATCH + b) * HID + j] = h;
        }
        __syncthreads();
        xg_val = xg_next;
    }

    if (j < HID) {
        cstate[b * HID + j] = c;
        hstate[b * HID + j] = h_lds[j];
    }
}

// ---------------- final FC ----------------
__global__ __launch_bounds__(512)
void fc_kernel(const float* __restrict__ hstate, const float* __restrict__ fcw,
               const float* __restrict__ fcb, float* __restrict__ out)
{
    int idx = threadIdx.x;      // 512 = 256 rows x 2 outs
    int b = idx >> 1, o = idx & 1;
    float acc = fcb[o];
    #pragma unroll
    for (int k = 0; k < HID; ++k)
        acc = fmaf(hstate[b * HID + k], fcw[o * HID + k], acc);
    out[b * 2 + o] = acc;
}

extern "C" void kernel_launch(void* const* d_in, const int* in_sizes, int n_in,
                              void* d_out, int out_size, void* d_ws, size_t ws_size,
                              hipStream_t stream)
{
    const float* x = (const float*)d_in[0];
    const float* w_ih[4]; const float* w_hh[4];
    const float* b_ih[4]; const float* b_hh[4];
    for (int l = 0; l < 4; ++l) {
        w_ih[l] = (const float*)d_in[1 + 4 * l];
        w_hh[l] = (const float*)d_in[2 + 4 * l];
        b_ih[l] = (const float*)d_in[3 + 4 * l];
        b_hh[l] = (const float*)d_in[4 + 4 * l];
    }
    const float* fc_w = (const float*)d_in[17];
    const float* fc_b = (const float*)d_in[18];
    float* out = (float*)d_out;

    char* wsb = (char*)d_ws;
    float* io  = (float*)wsb;                                   // 67,108,864 B
    float* xg  = (float*)(wsb + 67108864);                      // 33,554,432 B
    float* hst = (float*)(wsb + 67108864 + 33554432);           // 131,072 B
    float* cst = hst + BATCH * HID;                             // 131,072 B

    dim3 ggrid(256, 8);
    for (int l = 0; l < 4; ++l) {
        for (int cchunk = 0; cchunk < TSTEPS / TC; ++cchunk) {
            int t0 = cchunk * TC;
            if (l == 0)
                gemm_xg<100, true><<<ggrid, 256, 0, stream>>>(x, w_ih[0], b_ih[0], b_hh[0], xg, t0);
            else
                gemm_xg<128, false><<<ggrid, 256, 0, stream>>>(io, w_ih[l], b_ih[l], b_hh[l], xg, t0);
            lstm_rec<<<256, 512, 0, stream>>>(xg, w_hh[l], io, hst, cst, t0, cchunk == 0 ? 1 : 0);
        }
    }
    fc_kernel<<<1, 512, 0, stream>>>(hst, fc_w, fc_b, out);
}

// Round 2
// 3059.637 us; speedup vs baseline: 2.5537x; 2.5537x over previous
//
#include <hip/hip_runtime.h>

// LSTM: 4 layers, T=512, B=256, INPUT=100, H=128, gates=512 (i,f,g,o)
// Round 1: fp32 throughout.
//  - gemm_xg: BK=32, unroll-8, launch_bounds(256,4) => no spills (round-0 had
//    VGPR=256 + 872MB/dispatch of spill writes). XCD-aware block remap.
//  - lstm_rec: quad scheme. thread (q,p): all 4 gates of unit q over k-slice
//    [32p,32p+32). Quad butterfly shfl_xor -> every lane has i,f,g,o. One
//    barrier/step, double-buffered h in LDS (pad 4/32 to kill p-group bank
//    conflicts on ds_read_b128).
// ws: io [512*256*128]f32 @0 (67MB) | xg [64*256*512]f32 @67MB (33.5MB)
//     | hstate,cstate @100.6MB  => ~101MB total (known-safe size).

#define TSTEPS 512
#define BATCH  256
#define HID    128
#define GATES  512
#define TC     64

__device__ __forceinline__ float sigmoid_f(float x) {
    return 1.0f / (1.0f + __expf(-x));
}
__device__ __forceinline__ float tanh_f(float x) {
    float e = __expf(2.0f * x);
    return 1.0f - 2.0f / (e + 1.0f);
}

// ---------------- input-projection GEMM ----------------
// XG[r, j] = A[row r, :]·W[j, :] + b_ih[j] + b_hh[j]
// rows r = q*256 + b (t = t0+q), cols j in [0,512). 64x64 tile, 256 thr, 4x4.
template<int K, bool L0>
__global__ __launch_bounds__(256, 4)
void gemm_xg(const float* __restrict__ A, const float* __restrict__ W,
             const float* __restrict__ bih, const float* __restrict__ bhh,
             float* __restrict__ XG, int t0)
{
    __shared__ float As[32][68];  // As[kk][row]
    __shared__ float Bs[32][68];  // Bs[kk][col]
    const int tid  = threadIdx.x;
    // XCD-aware remap: HW round-robins flat%8 across XCDs. Make all 8
    // col-tiles of one row-tile share an XCD (A-tile L2 reuse).
    const int flat = blockIdx.y * 8 + blockIdx.x;   // [0,2048)
    const int rt   = flat & 255;   // row tile
    const int ct   = flat >> 8;    // col tile 0..7
    const int j0   = ct * 64;
    const int R0   = rt * 64;
    const int ty = tid >> 4, tx = tid & 15;

    float acc[4][4] = {};

    for (int kt = 0; kt < K; kt += 32) {
        #pragma unroll
        for (int i = 0; i < 8; ++i) {
            int f  = tid + 256 * i;
            int r  = f >> 5, kk = f & 31;   // 32 lanes span 32 consecutive k
            int k  = kt + kk;
            int Rg = R0 + r;
            int q  = Rg >> 8, b = Rg & 255;
            float av = 0.f, wv = 0.f;
            if (K == 128 || k < K) {
                av = L0 ? A[(b * TSTEPS + (t0 + q)) * K + k]
                        : A[((t0 + q) * BATCH + b) * K + k];
                wv = W[(j0 + r) * K + k];
            }
            As[kk][r] = av;
            Bs[kk][r] = wv;
        }
        __syncthreads();
        #pragma unroll 8
        for (int kk = 0; kk < 32; ++kk) {
            float4 a4 = *(const float4*)&As[kk][ty * 4];  // 16-lane broadcast
            float4 b4 = *(const float4*)&Bs[kk][tx * 4];  // 2-way alias (free)
            float aa[4] = {a4.x, a4.y, a4.z, a4.w};
            float bb[4] = {b4.x, b4.y, b4.z, b4.w};
            #pragma unroll
            for (int ii = 0; ii < 4; ++ii)
                #pragma unroll
                for (int jj = 0; jj < 4; ++jj)
                    acc[ii][jj] = fmaf(aa[ii], bb[jj], acc[ii][jj]);
        }
        __syncthreads();
    }

    float4 bi = *(const float4*)&bih[j0 + tx * 4];
    float4 bh = *(const float4*)&bhh[j0 + tx * 4];
    float bsum[4] = {bi.x + bh.x, bi.y + bh.y, bi.z + bh.z, bi.w + bh.w};
    #pragma unroll
    for (int ii = 0; ii < 4; ++ii) {
        int Rg = R0 + ty * 4 + ii;
        float4 st = {acc[ii][0] + bsum[0], acc[ii][1] + bsum[1],
                     acc[ii][2] + bsum[2], acc[ii][3] + bsum[3]};
        *(float4*)&XG[Rg * GATES + j0 + tx * 4] = st;
    }
}

// ---------------- recurrent scan ----------------
// One block per batch row. thread tid -> (q = tid>>2: hidden unit,
// p = tid&3: k-slice). Computes partials of gates i,f,g,o of unit q over
// h[32p..32p+32), quad butterfly sums slices; all lanes get full gates.
__global__ __launch_bounds__(512, 2)
void lstm_rec(const float* __restrict__ XG, const float* __restrict__ Whh,
              float* __restrict__ Hout,
              float* __restrict__ hstate, float* __restrict__ cstate,
              int t0, int first)
{
    const int b   = blockIdx.x;
    const int tid = threadIdx.x;
    const int q   = tid >> 2;
    const int p   = tid & 3;
    __shared__ float hbuf[2][144];  // unit u stored at u + 4*(u>>5)

    // w[g][m] = Whh[g*128+q][32p+m] : lane-contiguous 128B slices
    float w[4][32];
    #pragma unroll
    for (int g = 0; g < 4; ++g) {
        const float* wp = Whh + (g * HID + q) * HID + p * 32;
        #pragma unroll
        for (int j = 0; j < 8; ++j) {
            float4 v = *(const float4*)(wp + 4 * j);
            w[g][4*j+0] = v.x; w[g][4*j+1] = v.y;
            w[g][4*j+2] = v.z; w[g][4*j+3] = v.w;
        }
    }

    float c;
    if (first) {
        c = 0.f;
        if (tid < HID) hbuf[0][tid + 4 * (tid >> 5)] = 0.f;
    } else {
        c = cstate[b * HID + q];
        if (tid < HID) hbuf[0][tid + 4 * (tid >> 5)] = hstate[b * HID + tid];
    }
    __syncthreads();

    const float* xgp = XG + b * GATES + p * HID + q;
    float xg_val = xgp[0];
    float h = 0.f;
    int cur = 0;
    const int hbase = 36 * p;  // slice p base in padded layout (banks 4p+..)
    for (int s = 0; s < TC; ++s) {
        float xg_next = (s + 1 < TC) ? xgp[(s + 1) * (BATCH * GATES)] : 0.f;

        // partial gate sums over this lane's k-slice; fold xg into slot p
        float g0 = (p == 0) ? xg_val : 0.f;
        float g1 = (p == 1) ? xg_val : 0.f;
        float g2 = (p == 2) ? xg_val : 0.f;
        float g3 = (p == 3) ? xg_val : 0.f;
        #pragma unroll
        for (int j = 0; j < 8; ++j) {
            float4 hv = *(const float4*)&hbuf[cur][hbase + 4 * j];
            g0 = fmaf(w[0][4*j+0], hv.x, g0);
            g1 = fmaf(w[1][4*j+0], hv.x, g1);
            g2 = fmaf(w[2][4*j+0], hv.x, g2);
            g3 = fmaf(w[3][4*j+0], hv.x, g3);
            g0 = fmaf(w[0][4*j+1], hv.y, g0);
            g1 = fmaf(w[1][4*j+1], hv.y, g1);
            g2 = fmaf(w[2][4*j+1], hv.y, g2);
            g3 = fmaf(w[3][4*j+1], hv.y, g3);
            g0 = fmaf(w[0][4*j+2], hv.z, g0);
            g1 = fmaf(w[1][4*j+2], hv.z, g1);
            g2 = fmaf(w[2][4*j+2], hv.z, g2);
            g3 = fmaf(w[3][4*j+2], hv.z, g3);
            g0 = fmaf(w[0][4*j+3], hv.w, g0);
            g1 = fmaf(w[1][4*j+3], hv.w, g1);
            g2 = fmaf(w[2][4*j+3], hv.w, g2);
            g3 = fmaf(w[3][4*j+3], hv.w, g3);
        }
        // quad butterfly (DPP): all 4 lanes end with full i,f,g,o
        g0 += __shfl_xor(g0, 1); g0 += __shfl_xor(g0, 2);
        g1 += __shfl_xor(g1, 1); g1 += __shfl_xor(g1, 2);
        g2 += __shfl_xor(g2, 1); g2 += __shfl_xor(g2, 2);
        g3 += __shfl_xor(g3, 1); g3 += __shfl_xor(g3, 2);

        c = sigmoid_f(g1) * c + sigmoid_f(g0) * tanh_f(g2);
        h = sigmoid_f(g3) * tanh_f(c);

        if (p == 0) {
            hbuf[cur ^ 1][q + 4 * (q >> 5)] = h;
            Hout[((t0 + s) * BATCH + b) * HID + q] = h;
        }
        __syncthreads();  // single barrier: next step reads the other buffer
        cur ^= 1;
        xg_val = xg_next;
    }
    if (p == 0) {
        hstate[b * HID + q] = h;
        cstate[b * HID + q] = c;
    }
}

// ---------------- final FC ----------------
__global__ __launch_bounds__(512)
void fc_kernel(const float* __restrict__ hstate, const float* __restrict__ fcw,
               const float* __restrict__ fcb, float* __restrict__ out)
{
    int idx = threadIdx.x;      // 512 = 256 rows x 2 outs
    int b = idx >> 1, o = idx & 1;
    float acc = fcb[o];
    #pragma unroll
    for (int k = 0; k < HID; ++k)
        acc = fmaf(hstate[b * HID + k], fcw[o * HID + k], acc);
    out[b * 2 + o] = acc;
}

extern "C" void kernel_launch(void* const* d_in, const int* in_sizes, int n_in,
                              void* d_out, int out_size, void* d_ws, size_t ws_size,
                              hipStream_t stream)
{
    const float* x = (const float*)d_in[0];
    const float* w_ih[4]; const float* w_hh[4];
    const float* b_ih[4]; const float* b_hh[4];
    for (int l = 0; l < 4; ++l) {
        w_ih[l] = (const float*)d_in[1 + 4 * l];
        w_hh[l] = (const float*)d_in[2 + 4 * l];
        b_ih[l] = (const float*)d_in[3 + 4 * l];
        b_hh[l] = (const float*)d_in[4 + 4 * l];
    }
    const float* fc_w = (const float*)d_in[17];
    const float* fc_b = (const float*)d_in[18];
    float* out = (float*)d_out;

    char* wsb = (char*)d_ws;
    float* io  = (float*)wsb;                                   // 67,108,864 B
    float* xg  = (float*)(wsb + 67108864);                      // 33,554,432 B
    float* hst = (float*)(wsb + 67108864 + 33554432);           // 131,072 B
    float* cst = hst + BATCH * HID;                             // 131,072 B

    dim3 ggrid(8, 256);  // x = col tile (fast), y = row tile
    for (int l = 0; l < 4; ++l) {
        for (int cchunk = 0; cchunk < TSTEPS / TC; ++cchunk) {
            int t0 = cchunk * TC;
            if (l == 0)
                gemm_xg<100, true><<<ggrid, 256, 0, stream>>>(x, w_ih[0], b_ih[0], b_hh[0], xg, t0);
            else
                gemm_xg<128, false><<<ggrid, 256, 0, stream>>>(io, w_ih[l], b_ih[l], b_hh[l], xg, t0);
            lstm_rec<<<256, 512, 0, stream>>>(xg, w_hh[l], io, hst, cst, t0, cchunk == 0 ? 1 : 0);
        }
    }
    fc_kernel<<<1, 512, 0, stream>>>(hst, fc_w, fc_b, out);
}